// Round 17
// baseline (1000.645 us; speedup 1.0000x reference)
//
#include <hip/hip_runtime.h>
#include <hip/hip_bf16.h>
#include <math.h>

#define NN 20000
#define NE 640000
#define H  128
#define RB 50
#define NL 6
#define TBINS 4096
#define WBLK (128 * 136)

typedef unsigned short u16;
typedef __attribute__((ext_vector_type(8))) short short8v;
typedef __attribute__((ext_vector_type(4))) float f32x4;

// gather permutation (h/xn/tables): col c -> slot (c&15)*8 + (c>>4)
__device__ __forceinline__ u16 f2b(float v) {
  unsigned x = __float_as_uint(v);
  unsigned r = (x + 0x7FFFu + ((x >> 16) & 1u)) >> 16;
  return (u16)r;
}
__device__ __forceinline__ float b2f(u16 u) {
  return __uint_as_float(((unsigned int)u) << 16);
}

// ---------------- sort machinery ----------------
__global__ void k_zero_i32(int* __restrict__ p, int n) {
  int i = blockIdx.x * blockDim.x + threadIdx.x;
  if (i < n) p[i] = 0;
}
__global__ void k_hist(const int* __restrict__ ei, int* __restrict__ counts) {
  int e = blockIdx.x * blockDim.x + threadIdx.x;
  if (e < NE) atomicAdd(&counts[ei[NE + e]], 1);
}
__global__ __launch_bounds__(1024) void k_scan(const int* __restrict__ counts,
                                               int* __restrict__ cursor) {
  __shared__ int tsum[1024];
  int tid = threadIdx.x;
  int base = tid * 20;
  int s = 0;
  #pragma unroll
  for (int j = 0; j < 20; ++j) {
    int i = base + j;
    s += (i < NN) ? counts[i] : 0;
  }
  tsum[tid] = s;
  __syncthreads();
  for (int off = 1; off < 1024; off <<= 1) {
    int t = (tid >= off) ? tsum[tid - off] : 0;
    __syncthreads();
    tsum[tid] += t;
    __syncthreads();
  }
  int run = (tid > 0) ? tsum[tid - 1] : 0;
  #pragma unroll
  for (int j = 0; j < 20; ++j) {
    int i = base + j;
    if (i < NN) { cursor[i] = run; run += counts[i]; }
  }
}
__global__ void k_place(const int* __restrict__ ei, int* __restrict__ cursor,
                        int* __restrict__ perm) {
  int e = blockIdx.x * blockDim.x + threadIdx.x;
  if (e < NE) {
    int d = ei[NE + e];
    int p = atomicAdd(&cursor[d], 1);
    perm[p] = e;
  }
}

// ---------------- edge precompute: sorted src/tv only ----------------
__global__ void k_edge(const int* __restrict__ ei, const int* __restrict__ perm,
                       const float* __restrict__ pos,
                       int* __restrict__ srcS, float* __restrict__ tvS) {
  int p = blockIdx.x * 256 + threadIdx.x;
  if (p >= NE) return;
  int e = perm[p];
  int s = ei[e], t = ei[NE + e];
  srcS[p] = s;
  float dx = pos[3*s]   - pos[3*t];
  float dy = pos[3*s+1] - pos[3*t+1];
  float dz = pos[3*s+2] - pos[3*t+2];
  float d = sqrtf(dx*dx + dy*dy + dz*dz);
  tvS[p] = expf(-d);
}

// ---------------- filter tables: F_t(tv) in R^128, bf16, PERMUTED cols ----------------
__global__ __launch_bounds__(256) void k_tbuild(
    const float* __restrict__ means, const float* __restrict__ betas,
    const float* __restrict__ npW, const float* __restrict__ npb,
    const float* __restrict__ W1, const float* __restrict__ b1,
    const float* __restrict__ W2, const float* __restrict__ b2,
    u16* __restrict__ tb)
{
  int t  = blockIdx.x / (TBINS / 32);
  int j0 = (blockIdx.x % (TBINS / 32)) * 32;
  __shared__ float sAttr[32][52];
  __shared__ float sCut[32];
  __shared__ float sT[32][132];
  int tid = threadIdx.x;
  float tv0 = expf(-5.f);
  float dtv = (1.f - tv0) / (float)(TBINS - 1);
  for (int idx = tid; idx < 32 * RB; idx += 256) {
    int r = idx / RB, k = idx % RB;
    float tv = tv0 + (j0 + r) * dtv;
    float d = -logf(tv);
    float C = 0.5f * (cosf(d * 0.628318530717958647692f) + 1.f);
    if (d >= 5.f) C = 0.f;
    float diff = tv - means[k];
    sAttr[r][k] = C * expf(-betas[k] * diff * diff);
    if (k == 0) sCut[r] = C;
  }
  __syncthreads();
  int g = tid >> 5, c0 = (tid & 31) * 4, eb = g * 4;
  float acc[4][4];
  #pragma unroll
  for (int i = 0; i < 4; ++i)
    for (int j = 0; j < 4; ++j) acc[i][j] = 0.f;
  const float* Wa = (t == 0) ? npW : (W1 + (size_t)(t - 1) * RB * H);
  for (int k = 0; k < RB; ++k) {
    float4 wv = *(const float4*)&Wa[(size_t)k * H + c0];
    #pragma unroll
    for (int i = 0; i < 4; ++i) {
      float a = sAttr[eb + i][k];
      acc[i][0] += a * wv.x; acc[i][1] += a * wv.y;
      acc[i][2] += a * wv.z; acc[i][3] += a * wv.w;
    }
  }
  size_t obase = (size_t)t * TBINS * H;
  int pb = (c0 & 15) * 8 + (c0 >> 4);
  if (t == 0) {
    float4 b4 = *(const float4*)&npb[c0];
    float bvA[4] = {b4.x, b4.y, b4.z, b4.w};
    #pragma unroll
    for (int i = 0; i < 4; ++i) {
      float Cv = sCut[eb + i];
      size_t rb = obase + (size_t)(j0 + eb + i) * H;
      #pragma unroll
      for (int j = 0; j < 4; ++j)
        tb[rb + pb + 8 * j] = f2b((acc[i][j] + bvA[j]) * Cv);
    }
  } else {
    float4 b4 = *(const float4*)&b1[(size_t)(t - 1) * H + c0];
    float bvA[4] = {b4.x, b4.y, b4.z, b4.w};
    #pragma unroll
    for (int i = 0; i < 4; ++i) {
      #pragma unroll
      for (int j = 0; j < 4; ++j) {
        float v = acc[i][j] + bvA[j];
        sT[eb + i][c0 + j] = v / (1.f + __expf(-v));
      }
    }
    __syncthreads();
    #pragma unroll
    for (int i = 0; i < 4; ++i)
      for (int j = 0; j < 4; ++j) acc[i][j] = 0.f;
    const float* Wb = W2 + (size_t)(t - 1) * H * H;
    for (int k = 0; k < H; ++k) {
      float4 wv = *(const float4*)&Wb[(size_t)k * H + c0];
      #pragma unroll
      for (int i = 0; i < 4; ++i) {
        float a = sT[eb + i][k];
        acc[i][0] += a * wv.x; acc[i][1] += a * wv.y;
        acc[i][2] += a * wv.z; acc[i][3] += a * wv.w;
      }
    }
    float4 b24 = *(const float4*)&b2[(size_t)(t - 1) * H + c0];
    float bvB[4] = {b24.x, b24.y, b24.z, b24.w};
    #pragma unroll
    for (int i = 0; i < 4; ++i) {
      float Cv = sCut[eb + i];
      size_t rb = obase + (size_t)(j0 + eb + i) * H;
      #pragma unroll
      for (int j = 0; j < 4; ++j)
        tb[rb + pb + 8 * j] = f2b((acc[i][j] + bvB[j]) * Cv);
    }
  }
}

// ---------------- weight transpose to bf16 [n][k] stride 136 ----------------
__global__ void k_prepw2(const float* __restrict__ l2W, const float* __restrict__ lW,
                         const float* __restrict__ l1W, const float* __restrict__ cW,
                         u16* __restrict__ wt) {
  int i = blockIdx.x * 256 + threadIdx.x;
  if (i >= (3 * NL + 2) * WBLK) return;
  if (i < 3 * NL * WBLK) {
    int a = i / (NL * WBLK);
    int r = i % (NL * WBLK);
    int l = r / WBLK;
    int r2 = r % WBLK;
    int n = r2 / 136, k = r2 % 136;
    const float* src = (a == 0) ? l2W : (a == 1) ? lW : l1W;
    wt[i] = (k < H) ? f2b(src[(size_t)l * H * H + (size_t)k * H + n]) : (u16)0;
  } else {
    int j = i - 3 * NL * WBLK;
    int which = j / WBLK;
    int r2 = j % WBLK;
    int n = r2 / 136, k = r2 % 136;
    wt[i] = (k < H) ? f2b(cW[(size_t)(which * 128 + k) * H + n]) : (u16)0;
  }
}

// x f32 natural; xn bf16 PERMUTED
__global__ void k_embed(const int* __restrict__ z, const float* __restrict__ emb,
                        const float* __restrict__ nemb,
                        float* __restrict__ x, u16* __restrict__ xnb) {
  int i = blockIdx.x * blockDim.x + threadIdx.x;
  if (i >= NN * H) return;
  int n = i >> 7, c = i & (H - 1);
  long o = (long)z[n] * H + c;
  x[i] = emb[o];
  xnb[(size_t)n * H + ((c & 15) * 8 + (c >> 4))] = f2b(nemb[o]);
}

// ---------------- per-node edge walk (depth-3 pipelined), vsum in regs ----------------
__device__ __forceinline__ void edge_walk(
    int n, int r16, const int* __restrict__ counts, const int* __restrict__ cursor,
    const int* __restrict__ srcS, const float* __restrict__ tvS,
    const u16* __restrict__ tb, const u16* __restrict__ hsrc,
    int maskSelf, float tv0, float inv, float vsum[8])
{
  #pragma unroll
  for (int ct = 0; ct < 8; ++ct) vsum[ct] = 0.f;
  if (n >= NN) return;
  int cnt = counts[n];
  long e0 = (long)cursor[n] - cnt;   // cursor = end after k_place
  int P0_s = 0, P1_s = 0, P2_s = 0;
  float P0_w = 0.f, P1_w = 0.f, P2_w = 0.f;
  short8v P0_hv, P0_lo, P0_hi, P1_hv, P1_lo, P1_hi, P2_hv, P2_lo, P2_hi;
#define ISSUE(P, ii) { int _i = (ii); if (_i < cnt) { \
    long e = e0 + _i; \
    P##_s = srcS[e]; float tvv = tvS[e]; \
    P##_hv = *(const short8v*)&hsrc[(size_t)P##_s * H + r16 * 8]; \
    float u = fminf(fmaxf((tvv - tv0) * inv, 0.f), (float)(TBINS - 1) - 1e-3f); \
    int jj = (int)u; P##_w = u - (float)jj; \
    P##_lo = *(const short8v*)&tb[(size_t)jj * H + r16 * 8]; \
    P##_hi = *(const short8v*)&tb[(size_t)(jj + 1) * H + r16 * 8]; } }
#define CONSUME(P) { \
    float m = (maskSelf && P##_s == n) ? 0.f : 1.f; \
    _Pragma("unroll") \
    for (int ct = 0; ct < 8; ++ct) { \
      float lo = b2f((u16)P##_lo[ct]); \
      float hi = b2f((u16)P##_hi[ct]); \
      vsum[ct] += (lo + P##_w * (hi - lo)) * m * b2f((u16)P##_hv[ct]); \
    } }
  ISSUE(P0, 0); ISSUE(P1, 1); ISSUE(P2, 2);
  for (int i = 0; i < cnt; i += 3) {
    CONSUME(P0); ISSUE(P0, i + 3);
    if (i + 1 < cnt) { CONSUME(P1); ISSUE(P1, i + 4); }
    if (i + 2 < cnt) { CONSUME(P2); ISSUE(P2, i + 5); }
  }
#undef ISSUE
#undef CONSUME
}

// ---------------- FUSED layer: edge scatter -> LDS -> MFMA node chain ----------------
// x += silu(agg@W2+b2)@W3 + b3 ; hb = x@l1Wn   (agg never touches global)
__global__ __launch_bounds__(256) void k_fused(
    const int* __restrict__ counts, const int* __restrict__ cursor,
    const int* __restrict__ srcS, const float* __restrict__ tvS,
    const u16* __restrict__ tb, const u16* __restrict__ hsrc,
    const u16* __restrict__ W2t, const float* __restrict__ b2,
    const u16* __restrict__ W3t, const float* __restrict__ b3,
    const float* __restrict__ xin, float* __restrict__ xout,
    const u16* __restrict__ l1Wnt, u16* __restrict__ hb)
{
  __shared__ __align__(16) u16 sA[64 * 136];
  __shared__ __align__(16) u16 sT[64 * 136];
  int tid = threadIdx.x;
  int grp = tid >> 4, r16g = tid & 15;
  int n0 = blockIdx.x * 64;
  float tv0 = expf(-5.f);
  float inv = (float)(TBINS - 1) / (1.f - tv0);
  // edge phase: each 16-lane group owns 4 consecutive nodes
  for (int q = 0; q < 4; ++q) {
    int row = grp * 4 + q;
    int n = n0 + row;
    float vsum[8];
    edge_walk(n, r16g, counts, cursor, srcS, tvS, tb, hsrc, 0, tv0, inv, vsum);
    #pragma unroll
    for (int ct = 0; ct < 8; ++ct)
      sA[row * 136 + ct * 16 + r16g] = f2b(vsum[ct]);
  }
  __syncthreads();
  // MFMA phase
  int lane = tid & 63, wv = tid >> 6;
  int r16 = lane & 15, g4 = lane >> 4;
  int wrow = wv * 16;
  f32x4 acc[8];
  #pragma unroll
  for (int ct = 0; ct < 8; ++ct) acc[ct] = (f32x4){0.f, 0.f, 0.f, 0.f};
  #pragma unroll
  for (int kt = 0; kt < 4; ++kt) {
    short8v aF = *(const short8v*)&sA[(wrow + r16) * 136 + kt * 32 + g4 * 8];
    #pragma unroll
    for (int ct = 0; ct < 8; ++ct) {
      short8v bF = *(const short8v*)&W2t[(ct * 16 + r16) * 136 + kt * 32 + g4 * 8];
      acc[ct] = __builtin_amdgcn_mfma_f32_16x16x32_bf16(aF, bF, acc[ct], 0, 0, 0);
    }
  }
  #pragma unroll
  for (int ct = 0; ct < 8; ++ct) {
    float bb = b2[ct * 16 + r16];
    #pragma unroll
    for (int r = 0; r < 4; ++r) {
      float v = acc[ct][r] + bb;
      v = v / (1.f + __expf(-v));
      sT[(wrow + g4 * 4 + r) * 136 + ct * 16 + r16] = f2b(v);
    }
  }
  #pragma unroll
  for (int ct = 0; ct < 8; ++ct) acc[ct] = (f32x4){0.f, 0.f, 0.f, 0.f};
  #pragma unroll
  for (int kt = 0; kt < 4; ++kt) {
    short8v aF = *(const short8v*)&sT[(wrow + r16) * 136 + kt * 32 + g4 * 8];
    #pragma unroll
    for (int ct = 0; ct < 8; ++ct) {
      short8v bF = *(const short8v*)&W3t[(ct * 16 + r16) * 136 + kt * 32 + g4 * 8];
      acc[ct] = __builtin_amdgcn_mfma_f32_16x16x32_bf16(aF, bF, acc[ct], 0, 0, 0);
    }
  }
  #pragma unroll
  for (int ct = 0; ct < 8; ++ct) {
    float bb = b3[ct * 16 + r16];
    #pragma unroll
    for (int r = 0; r < 4; ++r) {
      int n = n0 + wrow + g4 * 4 + r;
      if (n < NN) {
        float o = acc[ct][r] + bb + xin[(size_t)n * H + ct * 16 + r16];
        xout[(size_t)n * H + ct * 16 + r16] = o;
        sA[(wrow + g4 * 4 + r) * 136 + ct * 16 + r16] = f2b(o);
      }
    }
  }
  if (!l1Wnt) return;
  #pragma unroll
  for (int ct = 0; ct < 8; ++ct) acc[ct] = (f32x4){0.f, 0.f, 0.f, 0.f};
  #pragma unroll
  for (int kt = 0; kt < 4; ++kt) {
    short8v aF = *(const short8v*)&sA[(wrow + r16) * 136 + kt * 32 + g4 * 8];
    #pragma unroll
    for (int ct = 0; ct < 8; ++ct) {
      short8v bF = *(const short8v*)&l1Wnt[(ct * 16 + r16) * 136 + kt * 32 + g4 * 8];
      acc[ct] = __builtin_amdgcn_mfma_f32_16x16x32_bf16(aF, bF, acc[ct], 0, 0, 0);
    }
  }
  #pragma unroll
  for (int r = 0; r < 4; ++r) {
    int n = n0 + wrow + g4 * 4 + r;
    if (n < NN) {
      short8v hv;
      #pragma unroll
      for (int ct = 0; ct < 8; ++ct) hv[ct] = (short)f2b(acc[ct][r]);
      *(short8v*)&hb[(size_t)n * H + r16 * 8] = hv;
    }
  }
}

// ---------------- FUSED combine: nbr edge scatter -> [x||agg]@cW + cb -> h0 ----------------
__global__ __launch_bounds__(256) void k_fusedC(
    const int* __restrict__ counts, const int* __restrict__ cursor,
    const int* __restrict__ srcS, const float* __restrict__ tvS,
    const u16* __restrict__ tb, const u16* __restrict__ xnb,
    const float* __restrict__ xb,
    const u16* __restrict__ cWt0, const u16* __restrict__ cWt1,
    const float* __restrict__ cb, const u16* __restrict__ l1W0t,
    float* __restrict__ xout, u16* __restrict__ hb)
{
  __shared__ __align__(16) u16 sX[64 * 136];
  __shared__ __align__(16) u16 sG[64 * 136];
  int tid = threadIdx.x;
  int grp = tid >> 4, r16g = tid & 15;
  int n0 = blockIdx.x * 64;
  float tv0 = expf(-5.f);
  float inv = (float)(TBINS - 1) / (1.f - tv0);
  // stage x -> bf16 sX (coalesced, fast)
  #pragma unroll
  for (int j = 0; j < 8; ++j) {
    int f4 = tid + j * 256;
    int r = f4 >> 5, c4 = f4 & 31;
    int n = n0 + r;
    float4 v = make_float4(0.f, 0.f, 0.f, 0.f);
    if (n < NN) v = *(const float4*)&xb[(size_t)n * H + c4 * 4];
    *(unsigned*)&sX[r * 136 + c4 * 4]     = (unsigned)f2b(v.x) | ((unsigned)f2b(v.y) << 16);
    *(unsigned*)&sX[r * 136 + c4 * 4 + 2] = (unsigned)f2b(v.z) | ((unsigned)f2b(v.w) << 16);
  }
  // edge phase (self-mask on)
  for (int q = 0; q < 4; ++q) {
    int row = grp * 4 + q;
    int n = n0 + row;
    float vsum[8];
    edge_walk(n, r16g, counts, cursor, srcS, tvS, tb, xnb, 1, tv0, inv, vsum);
    #pragma unroll
    for (int ct = 0; ct < 8; ++ct)
      sG[row * 136 + ct * 16 + r16g] = f2b(vsum[ct]);
  }
  __syncthreads();
  // MFMA: concat GEMM
  int lane = tid & 63, wv = tid >> 6;
  int r16 = lane & 15, g4 = lane >> 4;
  int wrow = wv * 16;
  f32x4 acc[8];
  #pragma unroll
  for (int ct = 0; ct < 8; ++ct) acc[ct] = (f32x4){0.f, 0.f, 0.f, 0.f};
  #pragma unroll
  for (int kt = 0; kt < 4; ++kt) {
    short8v aF = *(const short8v*)&sX[(wrow + r16) * 136 + kt * 32 + g4 * 8];
    #pragma unroll
    for (int ct = 0; ct < 8; ++ct) {
      short8v bF = *(const short8v*)&cWt0[(ct * 16 + r16) * 136 + kt * 32 + g4 * 8];
      acc[ct] = __builtin_amdgcn_mfma_f32_16x16x32_bf16(aF, bF, acc[ct], 0, 0, 0);
    }
  }
  #pragma unroll
  for (int kt = 0; kt < 4; ++kt) {
    short8v aF = *(const short8v*)&sG[(wrow + r16) * 136 + kt * 32 + g4 * 8];
    #pragma unroll
    for (int ct = 0; ct < 8; ++ct) {
      short8v bF = *(const short8v*)&cWt1[(ct * 16 + r16) * 136 + kt * 32 + g4 * 8];
      acc[ct] = __builtin_amdgcn_mfma_f32_16x16x32_bf16(aF, bF, acc[ct], 0, 0, 0);
    }
  }
  __syncthreads();   // sX re-use below
  #pragma unroll
  for (int ct = 0; ct < 8; ++ct) {
    float bb = cb[ct * 16 + r16];
    #pragma unroll
    for (int r = 0; r < 4; ++r) {
      int n = n0 + wrow + g4 * 4 + r;
      if (n < NN) {
        float o = acc[ct][r] + bb;
        xout[(size_t)n * H + ct * 16 + r16] = o;
        sX[(wrow + g4 * 4 + r) * 136 + ct * 16 + r16] = f2b(o);
      }
    }
  }
  // GEMM: h0 = xc @ l1W0 (wave-local rows)
  #pragma unroll
  for (int ct = 0; ct < 8; ++ct) acc[ct] = (f32x4){0.f, 0.f, 0.f, 0.f};
  #pragma unroll
  for (int kt = 0; kt < 4; ++kt) {
    short8v aF = *(const short8v*)&sX[(wrow + r16) * 136 + kt * 32 + g4 * 8];
    #pragma unroll
    for (int ct = 0; ct < 8; ++ct) {
      short8v bF = *(const short8v*)&l1W0t[(ct * 16 + r16) * 136 + kt * 32 + g4 * 8];
      acc[ct] = __builtin_amdgcn_mfma_f32_16x16x32_bf16(aF, bF, acc[ct], 0, 0, 0);
    }
  }
  #pragma unroll
  for (int r = 0; r < 4; ++r) {
    int n = n0 + wrow + g4 * 4 + r;
    if (n < NN) {
      short8v hv;
      #pragma unroll
      for (int ct = 0; ct < 8; ++ct) hv[ct] = (short)f2b(acc[ct][r]);
      *(short8v*)&hb[(size_t)n * H + r16 * 8] = hv;
    }
  }
}

// ---------------- launcher ----------------
extern "C" void kernel_launch(void* const* d_in, const int* in_sizes, int n_in,
                              void* d_out, int out_size, void* d_ws, size_t ws_size,
                              hipStream_t stream) {
  int bo = (n_in >= 4 && in_sizes[3] == NN) ? 0 : -1;  // batch present?
  const int*   z     = (const int*)d_in[0];
  const float* pos   = (const float*)d_in[1];
  const int*   ei    = (const int*)d_in[2];
  const float* emb   = (const float*)d_in[4 + bo];
  const float* nemb  = (const float*)d_in[5 + bo];
  const float* npW   = (const float*)d_in[6 + bo];
  const float* npb   = (const float*)d_in[7 + bo];
  const float* cW    = (const float*)d_in[8 + bo];
  const float* cb    = (const float*)d_in[9 + bo];
  const float* means = (const float*)d_in[10 + bo];
  const float* betas = (const float*)d_in[11 + bo];
  const float* W1    = (const float*)d_in[12 + bo];
  const float* b1    = (const float*)d_in[13 + bo];
  const float* W2    = (const float*)d_in[14 + bo];
  const float* b2    = (const float*)d_in[15 + bo];
  const float* l1W   = (const float*)d_in[16 + bo];
  const float* l2W   = (const float*)d_in[17 + bo];
  const float* l2b   = (const float*)d_in[18 + bo];
  const float* lW    = (const float*)d_in[19 + bo];
  const float* lb    = (const float*)d_in[20 + bo];

  char* w = (char*)d_ws;
  auto alloc = [&](size_t bytes) { char* p = w; w += (bytes + 255) & ~(size_t)255; return p; };
  int*   counts = (int*)  alloc((size_t)NN * 4);
  int*   cursor = (int*)  alloc((size_t)NN * 4);
  int*   perm   = (int*)  alloc((size_t)NE * 4);
  int*   srcS   = (int*)  alloc((size_t)NE * 4);
  float* tvS    = (float*)alloc((size_t)NE * 4);
  u16*   tb     = (u16*)  alloc((size_t)7 * TBINS * H * 2);
  u16*   wt     = (u16*)  alloc((size_t)(3 * NL + 2) * WBLK * 2);
  float* xbuf   = (float*)alloc((size_t)NN * H * 4);
  u16*   xnb    = (u16*)  alloc((size_t)NN * H * 2);
  u16*   hbA    = (u16*)  alloc((size_t)NN * H * 2);
  u16*   hbB    = (u16*)  alloc((size_t)NN * H * 2);

  u16* l2Wt = wt;
  u16* lWt  = wt + (size_t)NL * WBLK;
  u16* l1Wt = wt + (size_t)2 * NL * WBLK;
  u16* cWt0 = wt + (size_t)3 * NL * WBLK;
  u16* cWt1 = cWt0 + WBLK;

  dim3 b256(256);
  int gE256 = (NE + 255) / 256;        // 2500
  int gNH   = (NN * H + 255) / 256;    // 10000
  int gM    = (NN + 63) / 64;          // 313
  int gTB   = 7 * (TBINS / 32);        // 896
  int gPW   = ((3 * NL + 2) * WBLK + 255) / 256;

  k_zero_i32<<<(NN + 255) / 256, b256, 0, stream>>>(counts, NN);
  k_hist<<<gE256, b256, 0, stream>>>(ei, counts);
  k_scan<<<1, 1024, 0, stream>>>(counts, cursor);
  k_place<<<gE256, b256, 0, stream>>>(ei, cursor, perm);
  k_edge<<<gE256, b256, 0, stream>>>(ei, perm, pos, srcS, tvS);
  k_tbuild<<<gTB, b256, 0, stream>>>(means, betas, npW, npb, W1, b1, W2, b2, tb);
  k_prepw2<<<gPW, b256, 0, stream>>>(l2W, lW, l1W, cW, wt);
  k_embed<<<gNH, b256, 0, stream>>>(z, emb, nemb, xbuf, xnb);

  // fused neighbor-embedding + combine + l1W0  -> xbuf, hbA
  k_fusedC<<<gM, b256, 0, stream>>>(counts, cursor, srcS, tvS, tb, xnb, xbuf,
                                    cWt0, cWt1, cb, l1Wt, xbuf, hbA);

  u16* hin = hbA;
  u16* hout = hbB;
  for (int l = 0; l < NL; ++l) {
    const u16* l1Wnt = (l + 1 < NL) ? (l1Wt + (size_t)(l + 1) * WBLK) : nullptr;
    float* xo = (l == NL - 1) ? (float*)d_out : xbuf;
    k_fused<<<gM, b256, 0, stream>>>(counts, cursor, srcS, tvS,
                                     tb + (size_t)(1 + l) * TBINS * H, hin,
                                     l2Wt + (size_t)l * WBLK, l2b + (size_t)l * H,
                                     lWt + (size_t)l * WBLK, lb + (size_t)l * H,
                                     xbuf, xo, l1Wnt, hout);
    u16* tmp = hin; hin = hout; hout = tmp;
  }
}

// Round 18
// 734.924 us; speedup vs baseline: 1.3616x; 1.3616x over previous
//
#include <hip/hip_runtime.h>
#include <hip/hip_bf16.h>
#include <math.h>

#define NN 20000
#define NE 640000
#define H  128
#define RB 50
#define NL 6
#define TBINS 4096
#define WBLK (128 * 136)

typedef unsigned short u16;
typedef __attribute__((ext_vector_type(8))) short short8v;
typedef __attribute__((ext_vector_type(4))) float f32x4;

// gather permutation (h/xn/tables): col c -> slot (c&15)*8 + (c>>4)
__device__ __forceinline__ u16 f2b(float v) {
  unsigned x = __float_as_uint(v);
  unsigned r = (x + 0x7FFFu + ((x >> 16) & 1u)) >> 16;
  return (u16)r;
}
__device__ __forceinline__ float b2f(u16 u) {
  return __uint_as_float(((unsigned int)u) << 16);
}

// ---------------- sort machinery ----------------
__global__ void k_hist(const int* __restrict__ ei, int* __restrict__ counts) {
  int e = blockIdx.x * blockDim.x + threadIdx.x;
  if (e < NE) atomicAdd(&counts[ei[NE + e]], 1);
}
__global__ __launch_bounds__(1024) void k_scan(const int* __restrict__ counts,
                                               int* __restrict__ cursor) {
  __shared__ int tsum[1024];
  int tid = threadIdx.x;
  int base = tid * 20;
  int s = 0;
  #pragma unroll
  for (int j = 0; j < 20; ++j) {
    int i = base + j;
    s += (i < NN) ? counts[i] : 0;
  }
  tsum[tid] = s;
  __syncthreads();
  for (int off = 1; off < 1024; off <<= 1) {
    int t = (tid >= off) ? tsum[tid - off] : 0;
    __syncthreads();
    tsum[tid] += t;
    __syncthreads();
  }
  int run = (tid > 0) ? tsum[tid - 1] : 0;
  #pragma unroll
  for (int j = 0; j < 20; ++j) {
    int i = base + j;
    if (i < NN) { cursor[i] = run; run += counts[i]; }
  }
}
__global__ void k_place(const int* __restrict__ ei, int* __restrict__ cursor,
                        int* __restrict__ perm) {
  int e = blockIdx.x * blockDim.x + threadIdx.x;
  if (e < NE) {
    int d = ei[NE + e];
    int p = atomicAdd(&cursor[d], 1);
    perm[p] = e;
  }
}

// ---------------- edge precompute: sorted src/tv only ----------------
__global__ void k_edge(const int* __restrict__ ei, const int* __restrict__ perm,
                       const float* __restrict__ pos,
                       int* __restrict__ srcS, float* __restrict__ tvS) {
  int p = blockIdx.x * 256 + threadIdx.x;
  if (p >= NE) return;
  int e = perm[p];
  int s = ei[e], t = ei[NE + e];
  srcS[p] = s;
  float dx = pos[3*s]   - pos[3*t];
  float dy = pos[3*s+1] - pos[3*t+1];
  float dz = pos[3*s+2] - pos[3*t+2];
  float d = sqrtf(dx*dx + dy*dy + dz*dz);
  tvS[p] = expf(-d);
}

// ---------------- filter tables: F_t(tv) in R^128, bf16, PERMUTED cols ----------------
__global__ __launch_bounds__(256) void k_tbuild(
    const float* __restrict__ means, const float* __restrict__ betas,
    const float* __restrict__ npW, const float* __restrict__ npb,
    const float* __restrict__ W1, const float* __restrict__ b1,
    const float* __restrict__ W2, const float* __restrict__ b2,
    u16* __restrict__ tb)
{
  int t  = blockIdx.x / (TBINS / 32);
  int j0 = (blockIdx.x % (TBINS / 32)) * 32;
  __shared__ float sAttr[32][52];
  __shared__ float sCut[32];
  __shared__ float sT[32][132];
  int tid = threadIdx.x;
  float tv0 = expf(-5.f);
  float dtv = (1.f - tv0) / (float)(TBINS - 1);
  for (int idx = tid; idx < 32 * RB; idx += 256) {
    int r = idx / RB, k = idx % RB;
    float tv = tv0 + (j0 + r) * dtv;
    float d = -logf(tv);
    float C = 0.5f * (cosf(d * 0.628318530717958647692f) + 1.f);
    if (d >= 5.f) C = 0.f;
    float diff = tv - means[k];
    sAttr[r][k] = C * expf(-betas[k] * diff * diff);
    if (k == 0) sCut[r] = C;
  }
  __syncthreads();
  int g = tid >> 5, c0 = (tid & 31) * 4, eb = g * 4;
  float acc[4][4];
  #pragma unroll
  for (int i = 0; i < 4; ++i)
    for (int j = 0; j < 4; ++j) acc[i][j] = 0.f;
  const float* Wa = (t == 0) ? npW : (W1 + (size_t)(t - 1) * RB * H);
  for (int k = 0; k < RB; ++k) {
    float4 wv = *(const float4*)&Wa[(size_t)k * H + c0];
    #pragma unroll
    for (int i = 0; i < 4; ++i) {
      float a = sAttr[eb + i][k];
      acc[i][0] += a * wv.x; acc[i][1] += a * wv.y;
      acc[i][2] += a * wv.z; acc[i][3] += a * wv.w;
    }
  }
  size_t obase = (size_t)t * TBINS * H;
  int pb = (c0 & 15) * 8 + (c0 >> 4);
  if (t == 0) {
    float4 b4 = *(const float4*)&npb[c0];
    float bvA[4] = {b4.x, b4.y, b4.z, b4.w};
    #pragma unroll
    for (int i = 0; i < 4; ++i) {
      float Cv = sCut[eb + i];
      size_t rb = obase + (size_t)(j0 + eb + i) * H;
      #pragma unroll
      for (int j = 0; j < 4; ++j)
        tb[rb + pb + 8 * j] = f2b((acc[i][j] + bvA[j]) * Cv);
    }
  } else {
    float4 b4 = *(const float4*)&b1[(size_t)(t - 1) * H + c0];
    float bvA[4] = {b4.x, b4.y, b4.z, b4.w};
    #pragma unroll
    for (int i = 0; i < 4; ++i) {
      #pragma unroll
      for (int j = 0; j < 4; ++j) {
        float v = acc[i][j] + bvA[j];
        sT[eb + i][c0 + j] = v / (1.f + __expf(-v));
      }
    }
    __syncthreads();
    #pragma unroll
    for (int i = 0; i < 4; ++i)
      for (int j = 0; j < 4; ++j) acc[i][j] = 0.f;
    const float* Wb = W2 + (size_t)(t - 1) * H * H;
    for (int k = 0; k < H; ++k) {
      float4 wv = *(const float4*)&Wb[(size_t)k * H + c0];
      #pragma unroll
      for (int i = 0; i < 4; ++i) {
        float a = sT[eb + i][k];
        acc[i][0] += a * wv.x; acc[i][1] += a * wv.y;
        acc[i][2] += a * wv.z; acc[i][3] += a * wv.w;
      }
    }
    float4 b24 = *(const float4*)&b2[(size_t)(t - 1) * H + c0];
    float bvB[4] = {b24.x, b24.y, b24.z, b24.w};
    #pragma unroll
    for (int i = 0; i < 4; ++i) {
      float Cv = sCut[eb + i];
      size_t rb = obase + (size_t)(j0 + eb + i) * H;
      #pragma unroll
      for (int j = 0; j < 4; ++j)
        tb[rb + pb + 8 * j] = f2b((acc[i][j] + bvB[j]) * Cv);
    }
  }
}

// ---------------- weight transpose to bf16 [n][k] stride 136 ----------------
__global__ void k_prepw2(const float* __restrict__ l2W, const float* __restrict__ lW,
                         const float* __restrict__ l1W, const float* __restrict__ cW,
                         u16* __restrict__ wt) {
  int i = blockIdx.x * 256 + threadIdx.x;
  if (i >= (3 * NL + 2) * WBLK) return;
  if (i < 3 * NL * WBLK) {
    int a = i / (NL * WBLK);
    int r = i % (NL * WBLK);
    int l = r / WBLK;
    int r2 = r % WBLK;
    int n = r2 / 136, k = r2 % 136;
    const float* src = (a == 0) ? l2W : (a == 1) ? lW : l1W;
    wt[i] = (k < H) ? f2b(src[(size_t)l * H * H + (size_t)k * H + n]) : (u16)0;
  } else {
    int j = i - 3 * NL * WBLK;
    int which = j / WBLK;
    int r2 = j % WBLK;
    int n = r2 / 136, k = r2 % 136;
    wt[i] = (k < H) ? f2b(cW[(size_t)(which * 128 + k) * H + n]) : (u16)0;
  }
}

// x f32 natural; xn bf16 PERMUTED
__global__ void k_embed(const int* __restrict__ z, const float* __restrict__ emb,
                        const float* __restrict__ nemb,
                        float* __restrict__ x, u16* __restrict__ xnb) {
  int i = blockIdx.x * blockDim.x + threadIdx.x;
  if (i >= NN * H) return;
  int n = i >> 7, c = i & (H - 1);
  long o = (long)z[n] * H + c;
  x[i] = emb[o];
  xnb[(size_t)n * H + ((c & 15) * 8 + (c >> 4))] = f2b(nemb[o]);
}

// ---------------- dst-owned edge scatter: 2 nodes/group, 2x depth-3 chains ----------------
__global__ __launch_bounds__(256) void k_eso(
    const int* __restrict__ counts, const int* __restrict__ cursor,
    const int* __restrict__ srcS, const float* __restrict__ tvS,
    const u16* __restrict__ tb, const u16* __restrict__ hsrc,
    float* __restrict__ agg, int maskSelf)
{
  int tid = threadIdx.x;
  int grp = tid >> 4, r16 = tid & 15;
  int nA = blockIdx.x * 32 + grp * 2;
  int nB = nA + 1;
  int cntA = counts[nA], cntB = counts[nB];
  long e0A = (long)cursor[nA] - cntA;   // cursor = end after k_place
  long e0B = (long)cursor[nB] - cntB;
  float tv0 = expf(-5.f);
  float inv = (float)(TBINS - 1) / (1.f - tv0);
  float vsA[8], vsB[8];
  #pragma unroll
  for (int ct = 0; ct < 8; ++ct) { vsA[ct] = 0.f; vsB[ct] = 0.f; }
#define DECLS(P) int P##_s = 0; float P##_w = 0.f; short8v P##_hv, P##_lo, P##_hi;
  DECLS(A0) DECLS(A1) DECLS(A2) DECLS(B0) DECLS(B1) DECLS(B2)
#define ISSUE(P, e0, cnt, ii) { int _i = (ii); if (_i < cnt) { \
    long e = e0 + _i; \
    P##_s = srcS[e]; float tvv = tvS[e]; \
    P##_hv = *(const short8v*)&hsrc[(size_t)P##_s * H + r16 * 8]; \
    float u = fminf(fmaxf((tvv - tv0) * inv, 0.f), (float)(TBINS - 1) - 1e-3f); \
    int jj = (int)u; P##_w = u - (float)jj; \
    P##_lo = *(const short8v*)&tb[(size_t)jj * H + r16 * 8]; \
    P##_hi = *(const short8v*)&tb[(size_t)(jj + 1) * H + r16 * 8]; } }
#define CONSUME(P, nd, vs) { \
    float m = (maskSelf && P##_s == nd) ? 0.f : 1.f; \
    _Pragma("unroll") \
    for (int ct = 0; ct < 8; ++ct) { \
      float lo = b2f((u16)P##_lo[ct]); \
      float hi = b2f((u16)P##_hi[ct]); \
      vs[ct] += (lo + P##_w * (hi - lo)) * m * b2f((u16)P##_hv[ct]); \
    } }
  ISSUE(A0, e0A, cntA, 0); ISSUE(B0, e0B, cntB, 0);
  ISSUE(A1, e0A, cntA, 1); ISSUE(B1, e0B, cntB, 1);
  ISSUE(A2, e0A, cntA, 2); ISSUE(B2, e0B, cntB, 2);
  int mx = max(cntA, cntB);
  for (int i = 0; i < mx; i += 3) {
    if (i < cntA) { CONSUME(A0, nA, vsA); ISSUE(A0, e0A, cntA, i + 3); }
    if (i < cntB) { CONSUME(B0, nB, vsB); ISSUE(B0, e0B, cntB, i + 3); }
    if (i + 1 < cntA) { CONSUME(A1, nA, vsA); ISSUE(A1, e0A, cntA, i + 4); }
    if (i + 1 < cntB) { CONSUME(B1, nB, vsB); ISSUE(B1, e0B, cntB, i + 4); }
    if (i + 2 < cntA) { CONSUME(A2, nA, vsA); ISSUE(A2, e0A, cntA, i + 5); }
    if (i + 2 < cntB) { CONSUME(B2, nB, vsB); ISSUE(B2, e0B, cntB, i + 5); }
  }
#undef ISSUE
#undef CONSUME
#undef DECLS
  float* apA = agg + (size_t)nA * H + r16;
  float* apB = agg + (size_t)nB * H + r16;
  #pragma unroll
  for (int ct = 0; ct < 8; ++ct) { apA[ct * 16] = vsA[ct]; apB[ct * 16] = vsB[ct]; }
}

// ---------------- MFMA combine: x = [x||agg]@cW + cb; h0 = x@l1W0 ----------------
__global__ __launch_bounds__(256) void k_combineM(
    const float* __restrict__ xb, const float* __restrict__ ag,
    const u16* __restrict__ cWt0, const u16* __restrict__ cWt1,
    const float* __restrict__ cb, const u16* __restrict__ l1W0t,
    float* __restrict__ xout, u16* __restrict__ hb)
{
  __shared__ __align__(16) u16 sX[64 * 136];
  __shared__ __align__(16) u16 sG[64 * 136];
  int tid = threadIdx.x;
  int lane = tid & 63, wv = tid >> 6;
  int r16 = lane & 15, g4 = lane >> 4;
  int n0 = blockIdx.x * 64;
  #pragma unroll
  for (int j = 0; j < 8; ++j) {
    int f4 = tid + j * 256;
    int r = f4 >> 5, c4 = f4 & 31;
    int n = n0 + r;
    float4 vx = make_float4(0.f, 0.f, 0.f, 0.f);
    float4 vg = make_float4(0.f, 0.f, 0.f, 0.f);
    if (n < NN) {
      vx = *(const float4*)&xb[(size_t)n * H + c4 * 4];
      vg = *(const float4*)&ag[(size_t)n * H + c4 * 4];
    }
    *(unsigned*)&sX[r * 136 + c4 * 4]     = (unsigned)f2b(vx.x) | ((unsigned)f2b(vx.y) << 16);
    *(unsigned*)&sX[r * 136 + c4 * 4 + 2] = (unsigned)f2b(vx.z) | ((unsigned)f2b(vx.w) << 16);
    *(unsigned*)&sG[r * 136 + c4 * 4]     = (unsigned)f2b(vg.x) | ((unsigned)f2b(vg.y) << 16);
    *(unsigned*)&sG[r * 136 + c4 * 4 + 2] = (unsigned)f2b(vg.z) | ((unsigned)f2b(vg.w) << 16);
  }
  __syncthreads();
  int wrow = wv * 16;
  f32x4 acc[8];
  #pragma unroll
  for (int ct = 0; ct < 8; ++ct) acc[ct] = (f32x4){0.f, 0.f, 0.f, 0.f};
  #pragma unroll
  for (int kt = 0; kt < 4; ++kt) {
    short8v aF = *(const short8v*)&sX[(wrow + r16) * 136 + kt * 32 + g4 * 8];
    #pragma unroll
    for (int ct = 0; ct < 8; ++ct) {
      short8v bF = *(const short8v*)&cWt0[(ct * 16 + r16) * 136 + kt * 32 + g4 * 8];
      acc[ct] = __builtin_amdgcn_mfma_f32_16x16x32_bf16(aF, bF, acc[ct], 0, 0, 0);
    }
  }
  #pragma unroll
  for (int kt = 0; kt < 4; ++kt) {
    short8v aF = *(const short8v*)&sG[(wrow + r16) * 136 + kt * 32 + g4 * 8];
    #pragma unroll
    for (int ct = 0; ct < 8; ++ct) {
      short8v bF = *(const short8v*)&cWt1[(ct * 16 + r16) * 136 + kt * 32 + g4 * 8];
      acc[ct] = __builtin_amdgcn_mfma_f32_16x16x32_bf16(aF, bF, acc[ct], 0, 0, 0);
    }
  }
  #pragma unroll
  for (int ct = 0; ct < 8; ++ct) {
    float bb = cb[ct * 16 + r16];
    #pragma unroll
    for (int r = 0; r < 4; ++r) {
      int n = n0 + wrow + g4 * 4 + r;
      if (n < NN) {
        float o = acc[ct][r] + bb;
        xout[(size_t)n * H + ct * 16 + r16] = o;
        sX[(wrow + g4 * 4 + r) * 136 + ct * 16 + r16] = f2b(o);
      }
    }
  }
  #pragma unroll
  for (int ct = 0; ct < 8; ++ct) acc[ct] = (f32x4){0.f, 0.f, 0.f, 0.f};
  #pragma unroll
  for (int kt = 0; kt < 4; ++kt) {
    short8v aF = *(const short8v*)&sX[(wrow + r16) * 136 + kt * 32 + g4 * 8];
    #pragma unroll
    for (int ct = 0; ct < 8; ++ct) {
      short8v bF = *(const short8v*)&l1W0t[(ct * 16 + r16) * 136 + kt * 32 + g4 * 8];
      acc[ct] = __builtin_amdgcn_mfma_f32_16x16x32_bf16(aF, bF, acc[ct], 0, 0, 0);
    }
  }
  #pragma unroll
  for (int r = 0; r < 4; ++r) {
    int n = n0 + wrow + g4 * 4 + r;
    if (n < NN) {
      short8v hv;
      #pragma unroll
      for (int ct = 0; ct < 8; ++ct) hv[ct] = (short)f2b(acc[ct][r]);
      *(short8v*)&hb[(size_t)n * H + r16 * 8] = hv;
    }
  }
}

// ---------------- MFMA node chain, 32-row tiles, 128 threads ----------------
// x += silu(agg@W2+b2)@W3 + b3 ; hb = x@l1Wn
__global__ __launch_bounds__(128) void k_gemmM(
    const float* __restrict__ A, const u16* __restrict__ W2t, const float* __restrict__ b2,
    const u16* __restrict__ W3t, const float* __restrict__ b3,
    const float* __restrict__ xin, float* __restrict__ xout,
    const u16* __restrict__ l1Wnt, u16* __restrict__ hb)
{
  __shared__ __align__(16) u16 sA[32 * 136];
  __shared__ __align__(16) u16 sT[32 * 136];
  int tid = threadIdx.x;
  int lane = tid & 63, wv = tid >> 6;   // 2 waves
  int r16 = lane & 15, g4 = lane >> 4;
  int n0 = blockIdx.x * 32;             // NN = 625*32 exactly
  #pragma unroll
  for (int j = 0; j < 8; ++j) {
    int f4 = tid + j * 128;
    int r = f4 >> 5, c4 = f4 & 31;
    float4 v = *(const float4*)&A[(size_t)(n0 + r) * H + c4 * 4];
    *(unsigned*)&sA[r * 136 + c4 * 4]     = (unsigned)f2b(v.x) | ((unsigned)f2b(v.y) << 16);
    *(unsigned*)&sA[r * 136 + c4 * 4 + 2] = (unsigned)f2b(v.z) | ((unsigned)f2b(v.w) << 16);
  }
  __syncthreads();
  int wrow = wv * 16;
  f32x4 acc[8];
  #pragma unroll
  for (int ct = 0; ct < 8; ++ct) acc[ct] = (f32x4){0.f, 0.f, 0.f, 0.f};
  #pragma unroll
  for (int kt = 0; kt < 4; ++kt) {
    short8v aF = *(const short8v*)&sA[(wrow + r16) * 136 + kt * 32 + g4 * 8];
    #pragma unroll
    for (int ct = 0; ct < 8; ++ct) {
      short8v bF = *(const short8v*)&W2t[(ct * 16 + r16) * 136 + kt * 32 + g4 * 8];
      acc[ct] = __builtin_amdgcn_mfma_f32_16x16x32_bf16(aF, bF, acc[ct], 0, 0, 0);
    }
  }
  #pragma unroll
  for (int ct = 0; ct < 8; ++ct) {
    float bb = b2[ct * 16 + r16];
    #pragma unroll
    for (int r = 0; r < 4; ++r) {
      float v = acc[ct][r] + bb;
      v = v / (1.f + __expf(-v));
      sT[(wrow + g4 * 4 + r) * 136 + ct * 16 + r16] = f2b(v);
    }
  }
  #pragma unroll
  for (int ct = 0; ct < 8; ++ct) acc[ct] = (f32x4){0.f, 0.f, 0.f, 0.f};
  #pragma unroll
  for (int kt = 0; kt < 4; ++kt) {
    short8v aF = *(const short8v*)&sT[(wrow + r16) * 136 + kt * 32 + g4 * 8];
    #pragma unroll
    for (int ct = 0; ct < 8; ++ct) {
      short8v bF = *(const short8v*)&W3t[(ct * 16 + r16) * 136 + kt * 32 + g4 * 8];
      acc[ct] = __builtin_amdgcn_mfma_f32_16x16x32_bf16(aF, bF, acc[ct], 0, 0, 0);
    }
  }
  #pragma unroll
  for (int ct = 0; ct < 8; ++ct) {
    float bb = b3[ct * 16 + r16];
    #pragma unroll
    for (int r = 0; r < 4; ++r) {
      int n = n0 + wrow + g4 * 4 + r;
      float o = acc[ct][r] + bb + xin[(size_t)n * H + ct * 16 + r16];
      xout[(size_t)n * H + ct * 16 + r16] = o;
      sA[(wrow + g4 * 4 + r) * 136 + ct * 16 + r16] = f2b(o);
    }
  }
  if (!l1Wnt) return;
  #pragma unroll
  for (int ct = 0; ct < 8; ++ct) acc[ct] = (f32x4){0.f, 0.f, 0.f, 0.f};
  #pragma unroll
  for (int kt = 0; kt < 4; ++kt) {
    short8v aF = *(const short8v*)&sA[(wrow + r16) * 136 + kt * 32 + g4 * 8];
    #pragma unroll
    for (int ct = 0; ct < 8; ++ct) {
      short8v bF = *(const short8v*)&l1Wnt[(ct * 16 + r16) * 136 + kt * 32 + g4 * 8];
      acc[ct] = __builtin_amdgcn_mfma_f32_16x16x32_bf16(aF, bF, acc[ct], 0, 0, 0);
    }
  }
  #pragma unroll
  for (int r = 0; r < 4; ++r) {
    int n = n0 + wrow + g4 * 4 + r;
    short8v hv;
    #pragma unroll
    for (int ct = 0; ct < 8; ++ct) hv[ct] = (short)f2b(acc[ct][r]);
    *(short8v*)&hb[(size_t)n * H + r16 * 8] = hv;
  }
}

// ---------------- launcher ----------------
extern "C" void kernel_launch(void* const* d_in, const int* in_sizes, int n_in,
                              void* d_out, int out_size, void* d_ws, size_t ws_size,
                              hipStream_t stream) {
  int bo = (n_in >= 4 && in_sizes[3] == NN) ? 0 : -1;  // batch present?
  const int*   z     = (const int*)d_in[0];
  const float* pos   = (const float*)d_in[1];
  const int*   ei    = (const int*)d_in[2];
  const float* emb   = (const float*)d_in[4 + bo];
  const float* nemb  = (const float*)d_in[5 + bo];
  const float* npW   = (const float*)d_in[6 + bo];
  const float* npb   = (const float*)d_in[7 + bo];
  const float* cW    = (const float*)d_in[8 + bo];
  const float* cb    = (const float*)d_in[9 + bo];
  const float* means = (const float*)d_in[10 + bo];
  const float* betas = (const float*)d_in[11 + bo];
  const float* W1    = (const float*)d_in[12 + bo];
  const float* b1    = (const float*)d_in[13 + bo];
  const float* W2    = (const float*)d_in[14 + bo];
  const float* b2    = (const float*)d_in[15 + bo];
  const float* l1W   = (const float*)d_in[16 + bo];
  const float* l2W   = (const float*)d_in[17 + bo];
  const float* l2b   = (const float*)d_in[18 + bo];
  const float* lW    = (const float*)d_in[19 + bo];
  const float* lb    = (const float*)d_in[20 + bo];

  char* w = (char*)d_ws;
  auto alloc = [&](size_t bytes) { char* p = w; w += (bytes + 255) & ~(size_t)255; return p; };
  int*   counts = (int*)  alloc((size_t)NN * 4);
  int*   cursor = (int*)  alloc((size_t)NN * 4);
  int*   perm   = (int*)  alloc((size_t)NE * 4);
  int*   srcS   = (int*)  alloc((size_t)NE * 4);
  float* tvS    = (float*)alloc((size_t)NE * 4);
  u16*   tb     = (u16*)  alloc((size_t)7 * TBINS * H * 2);
  u16*   wt     = (u16*)  alloc((size_t)(3 * NL + 2) * WBLK * 2);
  float* xbuf   = (float*)alloc((size_t)NN * H * 4);
  float* agg    = (float*)alloc((size_t)NN * H * 4);
  u16*   xnb    = (u16*)  alloc((size_t)NN * H * 2);
  u16*   hbA    = (u16*)  alloc((size_t)NN * H * 2);
  u16*   hbB    = (u16*)  alloc((size_t)NN * H * 2);

  u16* l2Wt = wt;
  u16* lWt  = wt + (size_t)NL * WBLK;
  u16* l1Wt = wt + (size_t)2 * NL * WBLK;
  u16* cWt0 = wt + (size_t)3 * NL * WBLK;
  u16* cWt1 = cWt0 + WBLK;

  dim3 b256(256);
  int gE256 = (NE + 255) / 256;        // 2500
  int gNH   = (NN * H + 255) / 256;    // 10000
  int gESO  = NN / 32;                 // 625
  int gC    = (NN + 63) / 64;          // 313
  int gM    = NN / 32;                 // 625
  int gTB   = 7 * (TBINS / 32);        // 896
  int gPW   = ((3 * NL + 2) * WBLK + 255) / 256;

  hipMemsetAsync(counts, 0, (size_t)NN * 4, stream);
  k_hist<<<gE256, b256, 0, stream>>>(ei, counts);
  k_scan<<<1, 1024, 0, stream>>>(counts, cursor);
  k_place<<<gE256, b256, 0, stream>>>(ei, cursor, perm);
  k_edge<<<gE256, b256, 0, stream>>>(ei, perm, pos, srcS, tvS);
  k_tbuild<<<gTB, b256, 0, stream>>>(means, betas, npW, npb, W1, b1, W2, b2, tb);
  k_prepw2<<<gPW, b256, 0, stream>>>(l2W, lW, l1W, cW, wt);
  k_embed<<<gNH, b256, 0, stream>>>(z, emb, nemb, xbuf, xnb);

  // neighbor embedding (table 0, self-mask on)
  k_eso<<<gESO, b256, 0, stream>>>(counts, cursor, srcS, tvS, tb, xnb, agg, 1);
  k_combineM<<<gC, b256, 0, stream>>>(xbuf, agg, cWt0, cWt1, cb, l1Wt, xbuf, hbA);

  u16* hin = hbA;
  u16* hout = hbB;
  for (int l = 0; l < NL; ++l) {
    k_eso<<<gESO, b256, 0, stream>>>(counts, cursor, srcS, tvS,
                                     tb + (size_t)(1 + l) * TBINS * H,
                                     hin, agg, 0);
    const u16* l1Wnt = (l + 1 < NL) ? (l1Wt + (size_t)(l + 1) * WBLK) : nullptr;
    float* xo = (l == NL - 1) ? (float*)d_out : xbuf;
    k_gemmM<<<gM, dim3(128), 0, stream>>>(agg, l2Wt + (size_t)l * WBLK, l2b + (size_t)l * H,
                                          lWt + (size_t)l * WBLK, lb + (size_t)l * H,
                                          xbuf, xo, l1Wnt, hout);
    u16* tmp = hin; hin = hout; hout = tmp;
  }
}

// Round 19
// 561.513 us; speedup vs baseline: 1.7821x; 1.3088x over previous
//
#include <hip/hip_runtime.h>
#include <hip/hip_bf16.h>
#include <math.h>

#define NN 20000
#define NE 640000
#define H  128
#define RB 50
#define NL 6
#define TBINS 4096
#define WBLK (128 * 136)

typedef unsigned short u16;
typedef __attribute__((ext_vector_type(8))) short short8v;
typedef __attribute__((ext_vector_type(4))) float f32x4;

// gather permutation (h/xn/tables): col c -> slot (c&15)*8 + (c>>4)
__device__ __forceinline__ u16 f2b(float v) {
  unsigned x = __float_as_uint(v);
  unsigned r = (x + 0x7FFFu + ((x >> 16) & 1u)) >> 16;
  return (u16)r;
}
__device__ __forceinline__ float b2f(u16 u) {
  return __uint_as_float(((unsigned int)u) << 16);
}

// ---------------- sort machinery ----------------
__global__ void k_hist(const int* __restrict__ ei, int* __restrict__ counts) {
  int e = blockIdx.x * blockDim.x + threadIdx.x;
  if (e < NE) atomicAdd(&counts[ei[NE + e]], 1);
}
__global__ __launch_bounds__(1024) void k_scan(const int* __restrict__ counts,
                                               int* __restrict__ cursor) {
  __shared__ int tsum[1024];
  int tid = threadIdx.x;
  int base = tid * 20;
  int s = 0;
  #pragma unroll
  for (int j = 0; j < 20; ++j) {
    int i = base + j;
    s += (i < NN) ? counts[i] : 0;
  }
  tsum[tid] = s;
  __syncthreads();
  for (int off = 1; off < 1024; off <<= 1) {
    int t = (tid >= off) ? tsum[tid - off] : 0;
    __syncthreads();
    tsum[tid] += t;
    __syncthreads();
  }
  int run = (tid > 0) ? tsum[tid - 1] : 0;
  #pragma unroll
  for (int j = 0; j < 20; ++j) {
    int i = base + j;
    if (i < NN) { cursor[i] = run; run += counts[i]; }
  }
}
__global__ void k_place(const int* __restrict__ ei, int* __restrict__ cursor,
                        int* __restrict__ perm) {
  int e = blockIdx.x * blockDim.x + threadIdx.x;
  if (e < NE) {
    int d = ei[NE + e];
    int p = atomicAdd(&cursor[d], 1);
    perm[p] = e;
  }
}

// ---------------- edge precompute: sorted src/tv only ----------------
__global__ void k_edge(const int* __restrict__ ei, const int* __restrict__ perm,
                       const float* __restrict__ pos,
                       int* __restrict__ srcS, float* __restrict__ tvS) {
  int p = blockIdx.x * 256 + threadIdx.x;
  if (p >= NE) return;
  int e = perm[p];
  int s = ei[e], t = ei[NE + e];
  srcS[p] = s;
  float dx = pos[3*s]   - pos[3*t];
  float dy = pos[3*s+1] - pos[3*t+1];
  float dz = pos[3*s+2] - pos[3*t+2];
  float d = sqrtf(dx*dx + dy*dy + dz*dz);
  tvS[p] = expf(-d);
}

// ---------------- filter tables: F_t(tv) in R^128, bf16, PERMUTED cols ----------------
__global__ __launch_bounds__(256) void k_tbuild(
    const float* __restrict__ means, const float* __restrict__ betas,
    const float* __restrict__ npW, const float* __restrict__ npb,
    const float* __restrict__ W1, const float* __restrict__ b1,
    const float* __restrict__ W2, const float* __restrict__ b2,
    u16* __restrict__ tb)
{
  int t  = blockIdx.x / (TBINS / 32);
  int j0 = (blockIdx.x % (TBINS / 32)) * 32;
  __shared__ float sAttr[32][52];
  __shared__ float sCut[32];
  __shared__ float sT[32][132];
  int tid = threadIdx.x;
  float tv0 = expf(-5.f);
  float dtv = (1.f - tv0) / (float)(TBINS - 1);
  for (int idx = tid; idx < 32 * RB; idx += 256) {
    int r = idx / RB, k = idx % RB;
    float tv = tv0 + (j0 + r) * dtv;
    float d = -logf(tv);
    float C = 0.5f * (cosf(d * 0.628318530717958647692f) + 1.f);
    if (d >= 5.f) C = 0.f;
    float diff = tv - means[k];
    sAttr[r][k] = C * expf(-betas[k] * diff * diff);
    if (k == 0) sCut[r] = C;
  }
  __syncthreads();
  int g = tid >> 5, c0 = (tid & 31) * 4, eb = g * 4;
  float acc[4][4];
  #pragma unroll
  for (int i = 0; i < 4; ++i)
    for (int j = 0; j < 4; ++j) acc[i][j] = 0.f;
  const float* Wa = (t == 0) ? npW : (W1 + (size_t)(t - 1) * RB * H);
  for (int k = 0; k < RB; ++k) {
    float4 wv = *(const float4*)&Wa[(size_t)k * H + c0];
    #pragma unroll
    for (int i = 0; i < 4; ++i) {
      float a = sAttr[eb + i][k];
      acc[i][0] += a * wv.x; acc[i][1] += a * wv.y;
      acc[i][2] += a * wv.z; acc[i][3] += a * wv.w;
    }
  }
  size_t obase = (size_t)t * TBINS * H;
  int pb = (c0 & 15) * 8 + (c0 >> 4);
  if (t == 0) {
    float4 b4 = *(const float4*)&npb[c0];
    float bvA[4] = {b4.x, b4.y, b4.z, b4.w};
    #pragma unroll
    for (int i = 0; i < 4; ++i) {
      float Cv = sCut[eb + i];
      size_t rb = obase + (size_t)(j0 + eb + i) * H;
      #pragma unroll
      for (int j = 0; j < 4; ++j)
        tb[rb + pb + 8 * j] = f2b((acc[i][j] + bvA[j]) * Cv);
    }
  } else {
    float4 b4 = *(const float4*)&b1[(size_t)(t - 1) * H + c0];
    float bvA[4] = {b4.x, b4.y, b4.z, b4.w};
    #pragma unroll
    for (int i = 0; i < 4; ++i) {
      #pragma unroll
      for (int j = 0; j < 4; ++j) {
        float v = acc[i][j] + bvA[j];
        sT[eb + i][c0 + j] = v / (1.f + __expf(-v));
      }
    }
    __syncthreads();
    #pragma unroll
    for (int i = 0; i < 4; ++i)
      for (int j = 0; j < 4; ++j) acc[i][j] = 0.f;
    const float* Wb = W2 + (size_t)(t - 1) * H * H;
    for (int k = 0; k < H; ++k) {
      float4 wv = *(const float4*)&Wb[(size_t)k * H + c0];
      #pragma unroll
      for (int i = 0; i < 4; ++i) {
        float a = sT[eb + i][k];
        acc[i][0] += a * wv.x; acc[i][1] += a * wv.y;
        acc[i][2] += a * wv.z; acc[i][3] += a * wv.w;
      }
    }
    float4 b24 = *(const float4*)&b2[(size_t)(t - 1) * H + c0];
    float bvB[4] = {b24.x, b24.y, b24.z, b24.w};
    #pragma unroll
    for (int i = 0; i < 4; ++i) {
      float Cv = sCut[eb + i];
      size_t rb = obase + (size_t)(j0 + eb + i) * H;
      #pragma unroll
      for (int j = 0; j < 4; ++j)
        tb[rb + pb + 8 * j] = f2b((acc[i][j] + bvB[j]) * Cv);
    }
  }
}

// ---------------- weight transpose to bf16 [n][k] stride 136 ----------------
__global__ void k_prepw2(const float* __restrict__ l2W, const float* __restrict__ lW,
                         const float* __restrict__ l1W, const float* __restrict__ cW,
                         u16* __restrict__ wt) {
  int i = blockIdx.x * 256 + threadIdx.x;
  if (i >= (3 * NL + 2) * WBLK) return;
  if (i < 3 * NL * WBLK) {
    int a = i / (NL * WBLK);
    int r = i % (NL * WBLK);
    int l = r / WBLK;
    int r2 = r % WBLK;
    int n = r2 / 136, k = r2 % 136;
    const float* src = (a == 0) ? l2W : (a == 1) ? lW : l1W;
    wt[i] = (k < H) ? f2b(src[(size_t)l * H * H + (size_t)k * H + n]) : (u16)0;
  } else {
    int j = i - 3 * NL * WBLK;
    int which = j / WBLK;
    int r2 = j % WBLK;
    int n = r2 / 136, k = r2 % 136;
    wt[i] = (k < H) ? f2b(cW[(size_t)(which * 128 + k) * H + n]) : (u16)0;
  }
}

// x f32 natural; xn bf16 PERMUTED
__global__ void k_embed(const int* __restrict__ z, const float* __restrict__ emb,
                        const float* __restrict__ nemb,
                        float* __restrict__ x, u16* __restrict__ xnb) {
  int i = blockIdx.x * blockDim.x + threadIdx.x;
  if (i >= NN * H) return;
  int n = i >> 7, c = i & (H - 1);
  long o = (long)z[n] * H + c;
  x[i] = emb[o];
  xnb[(size_t)n * H + ((c & 15) * 8 + (c >> 4))] = f2b(nemb[o]);
}

// ---------------- dst-owned edge scatter (round-16 exact): 1 node/group, depth-3 ----------------
__global__ __launch_bounds__(256) void k_eso(
    const int* __restrict__ counts, const int* __restrict__ cursor,
    const int* __restrict__ srcS, const float* __restrict__ tvS,
    const u16* __restrict__ tb, const u16* __restrict__ hsrc,
    float* __restrict__ agg, int maskSelf)
{
  int tid = threadIdx.x;
  int n = blockIdx.x * 16 + (tid >> 4);
  int r16 = tid & 15;
  int cnt = counts[n];
  long e0 = (long)cursor[n] - cnt;   // cursor = end after k_place
  float tv0 = expf(-5.f);
  float inv = (float)(TBINS - 1) / (1.f - tv0);
  float vsum[8];
  #pragma unroll
  for (int ct = 0; ct < 8; ++ct) vsum[ct] = 0.f;
  int P0_s = 0, P1_s = 0, P2_s = 0;
  float P0_w = 0.f, P1_w = 0.f, P2_w = 0.f;
  short8v P0_hv, P0_lo, P0_hi, P1_hv, P1_lo, P1_hi, P2_hv, P2_lo, P2_hi;
#define ISSUE(P, ii) { int _i = (ii); if (_i < cnt) { \
    long e = e0 + _i; \
    P##_s = srcS[e]; float tvv = tvS[e]; \
    P##_hv = *(const short8v*)&hsrc[(size_t)P##_s * H + r16 * 8]; \
    float u = fminf(fmaxf((tvv - tv0) * inv, 0.f), (float)(TBINS - 1) - 1e-3f); \
    int jj = (int)u; P##_w = u - (float)jj; \
    P##_lo = *(const short8v*)&tb[(size_t)jj * H + r16 * 8]; \
    P##_hi = *(const short8v*)&tb[(size_t)(jj + 1) * H + r16 * 8]; } }
#define CONSUME(P) { \
    float m = (maskSelf && P##_s == n) ? 0.f : 1.f; \
    _Pragma("unroll") \
    for (int ct = 0; ct < 8; ++ct) { \
      float lo = b2f((u16)P##_lo[ct]); \
      float hi = b2f((u16)P##_hi[ct]); \
      vsum[ct] += (lo + P##_w * (hi - lo)) * m * b2f((u16)P##_hv[ct]); \
    } }
  ISSUE(P0, 0); ISSUE(P1, 1); ISSUE(P2, 2);
  for (int i = 0; i < cnt; i += 3) {
    CONSUME(P0); ISSUE(P0, i + 3);
    if (i + 1 < cnt) { CONSUME(P1); ISSUE(P1, i + 4); }
    if (i + 2 < cnt) { CONSUME(P2); ISSUE(P2, i + 5); }
  }
#undef ISSUE
#undef CONSUME
  float* ap = agg + (size_t)n * H + r16;
  #pragma unroll
  for (int ct = 0; ct < 8; ++ct) ap[ct * 16] = vsum[ct];
}

// ---------------- MFMA combine: x = [x||agg]@cW + cb; h0 = x@l1W0 ----------------
__global__ __launch_bounds__(256) void k_combineM(
    const float* __restrict__ xb, const float* __restrict__ ag,
    const u16* __restrict__ cWt0, const u16* __restrict__ cWt1,
    const float* __restrict__ cb, const u16* __restrict__ l1W0t,
    float* __restrict__ xout, u16* __restrict__ hb)
{
  __shared__ __align__(16) u16 sX[64 * 136];
  __shared__ __align__(16) u16 sG[64 * 136];
  int tid = threadIdx.x;
  int lane = tid & 63, wv = tid >> 6;
  int r16 = lane & 15, g4 = lane >> 4;
  int n0 = blockIdx.x * 64;
  #pragma unroll
  for (int j = 0; j < 8; ++j) {
    int f4 = tid + j * 256;
    int r = f4 >> 5, c4 = f4 & 31;
    int n = n0 + r;
    float4 vx = make_float4(0.f, 0.f, 0.f, 0.f);
    float4 vg = make_float4(0.f, 0.f, 0.f, 0.f);
    if (n < NN) {
      vx = *(const float4*)&xb[(size_t)n * H + c4 * 4];
      vg = *(const float4*)&ag[(size_t)n * H + c4 * 4];
    }
    *(unsigned*)&sX[r * 136 + c4 * 4]     = (unsigned)f2b(vx.x) | ((unsigned)f2b(vx.y) << 16);
    *(unsigned*)&sX[r * 136 + c4 * 4 + 2] = (unsigned)f2b(vx.z) | ((unsigned)f2b(vx.w) << 16);
    *(unsigned*)&sG[r * 136 + c4 * 4]     = (unsigned)f2b(vg.x) | ((unsigned)f2b(vg.y) << 16);
    *(unsigned*)&sG[r * 136 + c4 * 4 + 2] = (unsigned)f2b(vg.z) | ((unsigned)f2b(vg.w) << 16);
  }
  __syncthreads();
  int wrow = wv * 16;
  f32x4 acc[8];
  #pragma unroll
  for (int ct = 0; ct < 8; ++ct) acc[ct] = (f32x4){0.f, 0.f, 0.f, 0.f};
  #pragma unroll
  for (int kt = 0; kt < 4; ++kt) {
    short8v aF = *(const short8v*)&sX[(wrow + r16) * 136 + kt * 32 + g4 * 8];
    #pragma unroll
    for (int ct = 0; ct < 8; ++ct) {
      short8v bF = *(const short8v*)&cWt0[(ct * 16 + r16) * 136 + kt * 32 + g4 * 8];
      acc[ct] = __builtin_amdgcn_mfma_f32_16x16x32_bf16(aF, bF, acc[ct], 0, 0, 0);
    }
  }
  #pragma unroll
  for (int kt = 0; kt < 4; ++kt) {
    short8v aF = *(const short8v*)&sG[(wrow + r16) * 136 + kt * 32 + g4 * 8];
    #pragma unroll
    for (int ct = 0; ct < 8; ++ct) {
      short8v bF = *(const short8v*)&cWt1[(ct * 16 + r16) * 136 + kt * 32 + g4 * 8];
      acc[ct] = __builtin_amdgcn_mfma_f32_16x16x32_bf16(aF, bF, acc[ct], 0, 0, 0);
    }
  }
  #pragma unroll
  for (int ct = 0; ct < 8; ++ct) {
    float bb = cb[ct * 16 + r16];
    #pragma unroll
    for (int r = 0; r < 4; ++r) {
      int n = n0 + wrow + g4 * 4 + r;
      if (n < NN) {
        float o = acc[ct][r] + bb;
        xout[(size_t)n * H + ct * 16 + r16] = o;
        sX[(wrow + g4 * 4 + r) * 136 + ct * 16 + r16] = f2b(o);
      }
    }
  }
  #pragma unroll
  for (int ct = 0; ct < 8; ++ct) acc[ct] = (f32x4){0.f, 0.f, 0.f, 0.f};
  #pragma unroll
  for (int kt = 0; kt < 4; ++kt) {
    short8v aF = *(const short8v*)&sX[(wrow + r16) * 136 + kt * 32 + g4 * 8];
    #pragma unroll
    for (int ct = 0; ct < 8; ++ct) {
      short8v bF = *(const short8v*)&l1W0t[(ct * 16 + r16) * 136 + kt * 32 + g4 * 8];
      acc[ct] = __builtin_amdgcn_mfma_f32_16x16x32_bf16(aF, bF, acc[ct], 0, 0, 0);
    }
  }
  #pragma unroll
  for (int r = 0; r < 4; ++r) {
    int n = n0 + wrow + g4 * 4 + r;
    if (n < NN) {
      short8v hv;
      #pragma unroll
      for (int ct = 0; ct < 8; ++ct) hv[ct] = (short)f2b(acc[ct][r]);
      *(short8v*)&hb[(size_t)n * H + r16 * 8] = hv;
    }
  }
}

// ---------------- MFMA node chain, 32-row tiles, 128 threads ----------------
// x += silu(agg@W2+b2)@W3 + b3 ; hb = x@l1Wn
__global__ __launch_bounds__(128) void k_gemmM(
    const float* __restrict__ A, const u16* __restrict__ W2t, const float* __restrict__ b2,
    const u16* __restrict__ W3t, const float* __restrict__ b3,
    const float* __restrict__ xin, float* __restrict__ xout,
    const u16* __restrict__ l1Wnt, u16* __restrict__ hb)
{
  __shared__ __align__(16) u16 sA[32 * 136];
  __shared__ __align__(16) u16 sT[32 * 136];
  int tid = threadIdx.x;
  int lane = tid & 63, wv = tid >> 6;   // 2 waves
  int r16 = lane & 15, g4 = lane >> 4;
  int n0 = blockIdx.x * 32;             // NN = 625*32 exactly
  #pragma unroll
  for (int j = 0; j < 8; ++j) {
    int f4 = tid + j * 128;
    int r = f4 >> 5, c4 = f4 & 31;
    float4 v = *(const float4*)&A[(size_t)(n0 + r) * H + c4 * 4];
    *(unsigned*)&sA[r * 136 + c4 * 4]     = (unsigned)f2b(v.x) | ((unsigned)f2b(v.y) << 16);
    *(unsigned*)&sA[r * 136 + c4 * 4 + 2] = (unsigned)f2b(v.z) | ((unsigned)f2b(v.w) << 16);
  }
  __syncthreads();
  int wrow = wv * 16;
  f32x4 acc[8];
  #pragma unroll
  for (int ct = 0; ct < 8; ++ct) acc[ct] = (f32x4){0.f, 0.f, 0.f, 0.f};
  #pragma unroll
  for (int kt = 0; kt < 4; ++kt) {
    short8v aF = *(const short8v*)&sA[(wrow + r16) * 136 + kt * 32 + g4 * 8];
    #pragma unroll
    for (int ct = 0; ct < 8; ++ct) {
      short8v bF = *(const short8v*)&W2t[(ct * 16 + r16) * 136 + kt * 32 + g4 * 8];
      acc[ct] = __builtin_amdgcn_mfma_f32_16x16x32_bf16(aF, bF, acc[ct], 0, 0, 0);
    }
  }
  #pragma unroll
  for (int ct = 0; ct < 8; ++ct) {
    float bb = b2[ct * 16 + r16];
    #pragma unroll
    for (int r = 0; r < 4; ++r) {
      float v = acc[ct][r] + bb;
      v = v / (1.f + __expf(-v));
      sT[(wrow + g4 * 4 + r) * 136 + ct * 16 + r16] = f2b(v);
    }
  }
  #pragma unroll
  for (int ct = 0; ct < 8; ++ct) acc[ct] = (f32x4){0.f, 0.f, 0.f, 0.f};
  #pragma unroll
  for (int kt = 0; kt < 4; ++kt) {
    short8v aF = *(const short8v*)&sT[(wrow + r16) * 136 + kt * 32 + g4 * 8];
    #pragma unroll
    for (int ct = 0; ct < 8; ++ct) {
      short8v bF = *(const short8v*)&W3t[(ct * 16 + r16) * 136 + kt * 32 + g4 * 8];
      acc[ct] = __builtin_amdgcn_mfma_f32_16x16x32_bf16(aF, bF, acc[ct], 0, 0, 0);
    }
  }
  #pragma unroll
  for (int ct = 0; ct < 8; ++ct) {
    float bb = b3[ct * 16 + r16];
    #pragma unroll
    for (int r = 0; r < 4; ++r) {
      int n = n0 + wrow + g4 * 4 + r;
      float o = acc[ct][r] + bb + xin[(size_t)n * H + ct * 16 + r16];
      xout[(size_t)n * H + ct * 16 + r16] = o;
      sA[(wrow + g4 * 4 + r) * 136 + ct * 16 + r16] = f2b(o);
    }
  }
  if (!l1Wnt) return;
  #pragma unroll
  for (int ct = 0; ct < 8; ++ct) acc[ct] = (f32x4){0.f, 0.f, 0.f, 0.f};
  #pragma unroll
  for (int kt = 0; kt < 4; ++kt) {
    short8v aF = *(const short8v*)&sA[(wrow + r16) * 136 + kt * 32 + g4 * 8];
    #pragma unroll
    for (int ct = 0; ct < 8; ++ct) {
      short8v bF = *(const short8v*)&l1Wnt[(ct * 16 + r16) * 136 + kt * 32 + g4 * 8];
      acc[ct] = __builtin_amdgcn_mfma_f32_16x16x32_bf16(aF, bF, acc[ct], 0, 0, 0);
    }
  }
  #pragma unroll
  for (int r = 0; r < 4; ++r) {
    int n = n0 + wrow + g4 * 4 + r;
    short8v hv;
    #pragma unroll
    for (int ct = 0; ct < 8; ++ct) hv[ct] = (short)f2b(acc[ct][r]);
    *(short8v*)&hb[(size_t)n * H + r16 * 8] = hv;
  }
}

// ---------------- launcher ----------------
extern "C" void kernel_launch(void* const* d_in, const int* in_sizes, int n_in,
                              void* d_out, int out_size, void* d_ws, size_t ws_size,
                              hipStream_t stream) {
  int bo = (n_in >= 4 && in_sizes[3] == NN) ? 0 : -1;  // batch present?
  const int*   z     = (const int*)d_in[0];
  const float* pos   = (const float*)d_in[1];
  const int*   ei    = (const int*)d_in[2];
  const float* emb   = (const float*)d_in[4 + bo];
  const float* nemb  = (const float*)d_in[5 + bo];
  const float* npW   = (const float*)d_in[6 + bo];
  const float* npb   = (const float*)d_in[7 + bo];
  const float* cW    = (const float*)d_in[8 + bo];
  const float* cb    = (const float*)d_in[9 + bo];
  const float* means = (const float*)d_in[10 + bo];
  const float* betas = (const float*)d_in[11 + bo];
  const float* W1    = (const float*)d_in[12 + bo];
  const float* b1    = (const float*)d_in[13 + bo];
  const float* W2    = (const float*)d_in[14 + bo];
  const float* b2    = (const float*)d_in[15 + bo];
  const float* l1W   = (const float*)d_in[16 + bo];
  const float* l2W   = (const float*)d_in[17 + bo];
  const float* l2b   = (const float*)d_in[18 + bo];
  const float* lW    = (const float*)d_in[19 + bo];
  const float* lb    = (const float*)d_in[20 + bo];

  char* w = (char*)d_ws;
  auto alloc = [&](size_t bytes) { char* p = w; w += (bytes + 255) & ~(size_t)255; return p; };
  int*   counts = (int*)  alloc((size_t)NN * 4);
  int*   cursor = (int*)  alloc((size_t)NN * 4);
  int*   perm   = (int*)  alloc((size_t)NE * 4);
  int*   srcS   = (int*)  alloc((size_t)NE * 4);
  float* tvS    = (float*)alloc((size_t)NE * 4);
  u16*   tb     = (u16*)  alloc((size_t)7 * TBINS * H * 2);
  u16*   wt     = (u16*)  alloc((size_t)(3 * NL + 2) * WBLK * 2);
  float* xbuf   = (float*)alloc((size_t)NN * H * 4);
  float* agg    = (float*)alloc((size_t)NN * H * 4);
  u16*   xnb    = (u16*)  alloc((size_t)NN * H * 2);
  u16*   hbA    = (u16*)  alloc((size_t)NN * H * 2);
  u16*   hbB    = (u16*)  alloc((size_t)NN * H * 2);

  u16* l2Wt = wt;
  u16* lWt  = wt + (size_t)NL * WBLK;
  u16* l1Wt = wt + (size_t)2 * NL * WBLK;
  u16* cWt0 = wt + (size_t)3 * NL * WBLK;
  u16* cWt1 = cWt0 + WBLK;

  dim3 b256(256);
  int gE256 = (NE + 255) / 256;        // 2500
  int gNH   = (NN * H + 255) / 256;    // 10000
  int gESO  = NN / 16;                 // 1250
  int gC    = (NN + 63) / 64;          // 313
  int gM    = NN / 32;                 // 625
  int gTB   = 7 * (TBINS / 32);        // 896
  int gPW   = ((3 * NL + 2) * WBLK + 255) / 256;

  hipMemsetAsync(counts, 0, (size_t)NN * 4, stream);
  k_hist<<<gE256, b256, 0, stream>>>(ei, counts);
  k_scan<<<1, 1024, 0, stream>>>(counts, cursor);
  k_place<<<gE256, b256, 0, stream>>>(ei, cursor, perm);
  k_edge<<<gE256, b256, 0, stream>>>(ei, perm, pos, srcS, tvS);
  k_tbuild<<<gTB, b256, 0, stream>>>(means, betas, npW, npb, W1, b1, W2, b2, tb);
  k_prepw2<<<gPW, b256, 0, stream>>>(l2W, lW, l1W, cW, wt);
  k_embed<<<gNH, b256, 0, stream>>>(z, emb, nemb, xbuf, xnb);

  // neighbor embedding (table 0, self-mask on)
  k_eso<<<gESO, b256, 0, stream>>>(counts, cursor, srcS, tvS, tb, xnb, agg, 1);
  k_combineM<<<gC, b256, 0, stream>>>(xbuf, agg, cWt0, cWt1, cb, l1Wt, xbuf, hbA);

  u16* hin = hbA;
  u16* hout = hbB;
  for (int l = 0; l < NL; ++l) {
    k_eso<<<gESO, b256, 0, stream>>>(counts, cursor, srcS, tvS,
                                     tb + (size_t)(1 + l) * TBINS * H,
                                     hin, agg, 0);
    const u16* l1Wnt = (l + 1 < NL) ? (l1Wt + (size_t)(l + 1) * WBLK) : nullptr;
    float* xo = (l == NL - 1) ? (float*)d_out : xbuf;
    k_gemmM<<<gM, dim3(128), 0, stream>>>(agg, l2Wt + (size_t)l * WBLK, l2b + (size_t)l * H,
                                          lWt + (size_t)l * WBLK, lb + (size_t)l * H,
                                          xbuf, xo, l1Wnt, hout);
    u16* tmp = hin; hin = hout; hout = tmp;
  }
}